// Round 1
// baseline (889.031 us; speedup 1.0000x reference)
//
#include <hip/hip_runtime.h>

// ---------------------------------------------------------------------------
// Problem: B=8, R=128, H=W=4096
//   C    = alpha*I + 2*gamma * N @ N^T            [128x128], SPD, diag-dominant
//   out  = Ak_L @ (2*gamma * Cinv @ N)^T          [4096x128] per batch
// Pipeline:
//   k_castT : N fp32 [r][w] -> NT bf16 [w][r]   (for Mt's contiguous-k B-op)
//   k_gram  : Gpart[b][ks] = partial N*N^T (bf16 MFMA, K split by 4)
//   k_inv   : C = alpha*I + 2g*sum(Gpart); fp32 Gauss-Jordan -> Cinv (register-resident)
//   k_mt    : Mt = bf16(2g * Cinv @ N)  via MFMA (A=Cinv bf16, Bt=NT)
//   k_gemm  : out = A(fp32->bf16) @ Mt^T  -- memory-bound, 512 MB A stream
// ---------------------------------------------------------------------------

typedef __attribute__((ext_vector_type(8))) short bf16x8;
typedef __attribute__((ext_vector_type(4))) float f32x4;
typedef __attribute__((ext_vector_type(4))) unsigned int u32x4;

#define MFMA16(a, b, c) __builtin_amdgcn_mfma_f32_16x16x32_bf16((a), (b), (c), 0, 0, 0)

__device__ __forceinline__ unsigned short f2bf(float f) {
  union { float f; unsigned u; } v; v.f = f;
  unsigned u = v.u;
  return (unsigned short)((u + 0x7FFFu + ((u >> 16) & 1u)) >> 16);  // RNE
}
__device__ __forceinline__ unsigned pack2(float x, float y) {
  return (unsigned)f2bf(x) | ((unsigned)f2bf(y) << 16);
}

// ---------------------------------------------------------------------------
// Kernel 1: transposed cast  N[b][r][w] fp32 -> NT[b][w][r] bf16
// grid (64, 8), 256 thr; tile 128r x 64w through LDS
// ---------------------------------------------------------------------------
__global__ __launch_bounds__(256) void k_castT(const float* __restrict__ N,
                                               unsigned short* __restrict__ NT) {
  __attribute__((aligned(16))) __shared__ float tile[128 * 68];  // pad 68 vs 64
  int wc = blockIdx.x, b = blockIdx.y;
  const float* Nb = N + (size_t)b * 524288 + wc * 64;
  int t = threadIdx.x;
  int row = t >> 1, half = t & 1;  // 128 rows x 2 halves of 32 cols
  const float* src = Nb + (size_t)row * 4096 + half * 32;
  float* dst = tile + row * 68 + half * 32;
#pragma unroll
  for (int j = 0; j < 8; j++) *(f32x4*)(dst + j * 4) = *(const f32x4*)(src + j * 4);
  __syncthreads();
  int ow = t >> 2, q = t & 3;  // 64 out rows (w), each thread does r-range q*32..+32
  unsigned short* out = NT + (size_t)b * 524288 + (size_t)(wc * 64 + ow) * 128 + q * 32;
#pragma unroll
  for (int c = 0; c < 4; c++) {
    u32x4 p;
#pragma unroll
    for (int k = 0; k < 4; k++) {
      float f0 = tile[(q * 32 + c * 8 + k * 2) * 68 + ow];
      float f1 = tile[(q * 32 + c * 8 + k * 2 + 1) * 68 + ow];
      p[k] = pack2(f0, f1);
    }
    *(u32x4*)(out + c * 8) = p;
  }
}

// ---------------------------------------------------------------------------
// Kernel 2: Gram partials. grid (4 ksplit, 8 batch), 256 thr.
// Gpart[b][ks][128][128] fp32 = N[:, ks*1024 : +1024] @ same^T  (bf16 MFMA)
// LDS tile 128 x 64 bf16, padded row stride 72 (even bank spread for b128)
// ---------------------------------------------------------------------------
__global__ __launch_bounds__(256) void k_gram(const float* __restrict__ N,
                                              float* __restrict__ Gpart) {
  __attribute__((aligned(16))) __shared__ unsigned short lds[128 * 72];
  int ks = blockIdx.x, b = blockIdx.y;
  const float* Nb = N + (size_t)b * 524288 + ks * 1024;
  int t = threadIdx.x;
  int wave = t >> 6, lane = t & 63, quad = lane >> 4, l16 = lane & 15;
  f32x4 acc[2][8];
#pragma unroll
  for (int i = 0; i < 2; i++)
#pragma unroll
    for (int j = 0; j < 8; j++) acc[i][j] = (f32x4){0.f, 0.f, 0.f, 0.f};
  int srow = t >> 1, shalf = t & 1;
  const float* srcb = Nb + (size_t)srow * 4096 + shalf * 32;
  unsigned short* dptr = lds + srow * 72 + shalf * 32;
  for (int it = 0; it < 16; ++it) {
    u32x4 pk0, pk1;
    {
      f32x4 v0 = *(const f32x4*)(srcb + it * 64 + 0);
      f32x4 v1 = *(const f32x4*)(srcb + it * 64 + 4);
      f32x4 v2 = *(const f32x4*)(srcb + it * 64 + 8);
      f32x4 v3 = *(const f32x4*)(srcb + it * 64 + 12);
      pk0[0] = pack2(v0[0], v0[1]); pk0[1] = pack2(v0[2], v0[3]);
      pk0[2] = pack2(v1[0], v1[1]); pk0[3] = pack2(v1[2], v1[3]);
      pk1[0] = pack2(v2[0], v2[1]); pk1[1] = pack2(v2[2], v2[3]);
      pk1[2] = pack2(v3[0], v3[1]); pk1[3] = pack2(v3[2], v3[3]);
    }
    u32x4 pk2, pk3;
    {
      f32x4 v0 = *(const f32x4*)(srcb + it * 64 + 16);
      f32x4 v1 = *(const f32x4*)(srcb + it * 64 + 20);
      f32x4 v2 = *(const f32x4*)(srcb + it * 64 + 24);
      f32x4 v3 = *(const f32x4*)(srcb + it * 64 + 28);
      pk2[0] = pack2(v0[0], v0[1]); pk2[1] = pack2(v0[2], v0[3]);
      pk2[2] = pack2(v1[0], v1[1]); pk2[3] = pack2(v1[2], v1[3]);
      pk3[0] = pack2(v2[0], v2[1]); pk3[1] = pack2(v2[2], v2[3]);
      pk3[2] = pack2(v3[0], v3[1]); pk3[3] = pack2(v3[2], v3[3]);
    }
    __syncthreads();
    *(u32x4*)(dptr + 0) = pk0;
    *(u32x4*)(dptr + 8) = pk1;
    *(u32x4*)(dptr + 16) = pk2;
    *(u32x4*)(dptr + 24) = pk3;
    __syncthreads();
    bf16x8 af[2][2], bfv[8][2];
#pragma unroll
    for (int mt = 0; mt < 2; mt++)
#pragma unroll
      for (int kk = 0; kk < 2; kk++)
        af[mt][kk] = *(const bf16x8*)(lds + (wave * 32 + mt * 16 + l16) * 72 + (kk * 4 + quad) * 8);
#pragma unroll
    for (int nt = 0; nt < 8; nt++)
#pragma unroll
      for (int kk = 0; kk < 2; kk++)
        bfv[nt][kk] = *(const bf16x8*)(lds + (nt * 16 + l16) * 72 + (kk * 4 + quad) * 8);
#pragma unroll
    for (int mt = 0; mt < 2; mt++)
#pragma unroll
      for (int nt = 0; nt < 8; nt++)
#pragma unroll
        for (int kk = 0; kk < 2; kk++)
          acc[mt][nt] = MFMA16(af[mt][kk], bfv[nt][kk], acc[mt][nt]);
  }
  float* Gp = Gpart + ((size_t)(b * 4 + ks) << 14);
#pragma unroll
  for (int mt = 0; mt < 2; mt++)
#pragma unroll
    for (int nt = 0; nt < 8; nt++)
#pragma unroll
      for (int rg = 0; rg < 4; rg++) {
        int row = wave * 32 + mt * 16 + quad * 4 + rg;
        int col = nt * 16 + l16;
        Gp[row * 128 + col] = acc[mt][nt][rg];
      }
}

// ---------------------------------------------------------------------------
// Kernel 3: register-resident Gauss-Jordan inverse of C = alpha*I + 2g*G.
// grid (8), 1024 thr. Thread (rb,cg) owns rows 4rb..+3 x aug cols 8cg..+7.
// No pivoting (C is SPD + diagonally dominant). 2 barriers/step, dbl-buffered.
// ---------------------------------------------------------------------------
__global__ __launch_bounds__(1024) void k_inv(const float* __restrict__ Gpart,
                                              const float* __restrict__ alpha,
                                              const float* __restrict__ gamma,
                                              float* __restrict__ Cinv) {
  __attribute__((aligned(16))) __shared__ float Cs[16384];
  __attribute__((aligned(16))) __shared__ float mcol[2][128];
  __attribute__((aligned(16))) __shared__ float pivrow[2][256];
  int b = blockIdx.x;
  int t = threadIdx.x;
  const float* Gp = Gpart + ((size_t)b * 4 << 14);
#pragma unroll
  for (int c = 0; c < 4; c++) {
    int off = c * 4096 + t * 4;
    f32x4 v0 = *(const f32x4*)(Gp + off);
    f32x4 v1 = *(const f32x4*)(Gp + 16384 + off);
    f32x4 v2 = *(const f32x4*)(Gp + 32768 + off);
    f32x4 v3 = *(const f32x4*)(Gp + 49152 + off);
    *(f32x4*)(Cs + off) = v0 + v1 + v2 + v3;
  }
  __syncthreads();
  int rb = t & 31, cg = t >> 5;
  float al = alpha[b], ga2 = 2.f * gamma[b];
  float a[4][8];
#pragma unroll
  for (int i = 0; i < 4; i++) {
    int r = rb * 4 + i;
#pragma unroll
    for (int j = 0; j < 8; j++) {
      if (cg < 16) {
        int c = cg * 8 + j;
        a[i][j] = ga2 * Cs[r * 128 + c] + ((r == c) ? al : 0.f);
      } else {
        int c = (cg - 16) * 8 + j;
        a[i][j] = (r == c) ? 1.f : 0.f;
      }
    }
  }
  __syncthreads();
  for (int p = 0; p < 128; ++p) {
    int pb = p & 1;
    int cgp = p >> 3, jp = p & 7, rbp = p >> 2, ip = p & 3;
    if (cg == cgp) {  // capture column p (pre-elimination multipliers)
      float m0, m1, m2, m3;
      switch (jp) {
        case 0: m0 = a[0][0]; m1 = a[1][0]; m2 = a[2][0]; m3 = a[3][0]; break;
        case 1: m0 = a[0][1]; m1 = a[1][1]; m2 = a[2][1]; m3 = a[3][1]; break;
        case 2: m0 = a[0][2]; m1 = a[1][2]; m2 = a[2][2]; m3 = a[3][2]; break;
        case 3: m0 = a[0][3]; m1 = a[1][3]; m2 = a[2][3]; m3 = a[3][3]; break;
        case 4: m0 = a[0][4]; m1 = a[1][4]; m2 = a[2][4]; m3 = a[3][4]; break;
        case 5: m0 = a[0][5]; m1 = a[1][5]; m2 = a[2][5]; m3 = a[3][5]; break;
        case 6: m0 = a[0][6]; m1 = a[1][6]; m2 = a[2][6]; m3 = a[3][6]; break;
        default: m0 = a[0][7]; m1 = a[1][7]; m2 = a[2][7]; m3 = a[3][7]; break;
      }
      *(f32x4*)&mcol[pb][rb * 4] = (f32x4){m0, m1, m2, m3};
    }
    __syncthreads();
    if (rb == rbp) {  // scale pivot row, publish it
      float d = mcol[pb][p];
      float invd = 1.0f / d;
      switch (ip) {
        case 0: {
#pragma unroll
          for (int j = 0; j < 8; j++) a[0][j] *= invd;
          *(f32x4*)&pivrow[pb][cg * 8] = (f32x4){a[0][0], a[0][1], a[0][2], a[0][3]};
          *(f32x4*)&pivrow[pb][cg * 8 + 4] = (f32x4){a[0][4], a[0][5], a[0][6], a[0][7]};
        } break;
        case 1: {
#pragma unroll
          for (int j = 0; j < 8; j++) a[1][j] *= invd;
          *(f32x4*)&pivrow[pb][cg * 8] = (f32x4){a[1][0], a[1][1], a[1][2], a[1][3]};
          *(f32x4*)&pivrow[pb][cg * 8 + 4] = (f32x4){a[1][4], a[1][5], a[1][6], a[1][7]};
        } break;
        case 2: {
#pragma unroll
          for (int j = 0; j < 8; j++) a[2][j] *= invd;
          *(f32x4*)&pivrow[pb][cg * 8] = (f32x4){a[2][0], a[2][1], a[2][2], a[2][3]};
          *(f32x4*)&pivrow[pb][cg * 8 + 4] = (f32x4){a[2][4], a[2][5], a[2][6], a[2][7]};
        } break;
        default: {
#pragma unroll
          for (int j = 0; j < 8; j++) a[3][j] *= invd;
          *(f32x4*)&pivrow[pb][cg * 8] = (f32x4){a[3][0], a[3][1], a[3][2], a[3][3]};
          *(f32x4*)&pivrow[pb][cg * 8 + 4] = (f32x4){a[3][4], a[3][5], a[3][6], a[3][7]};
        } break;
      }
    }
    __syncthreads();
    f32x4 mc = *(const f32x4*)&mcol[pb][rb * 4];
    f32x4 p0 = *(const f32x4*)&pivrow[pb][cg * 8];
    f32x4 p1 = *(const f32x4*)&pivrow[pb][cg * 8 + 4];
#pragma unroll
    for (int i = 0; i < 4; i++) {
      int r = rb * 4 + i;
      float m = (r == p) ? 0.f : mc[i];
#pragma unroll
      for (int j = 0; j < 4; j++) a[i][j] -= m * p0[j];
#pragma unroll
      for (int j = 0; j < 4; j++) a[i][4 + j] -= m * p1[j];
    }
  }
  if (cg >= 16) {  // right half now holds C^{-1}
    float* dst = Cinv + ((size_t)b << 14);
    int c0 = (cg - 16) * 8;
#pragma unroll
    for (int i = 0; i < 4; i++) {
      int r = rb * 4 + i;
      *(f32x4*)(dst + r * 128 + c0) = (f32x4){a[i][0], a[i][1], a[i][2], a[i][3]};
      *(f32x4*)(dst + r * 128 + c0 + 4) = (f32x4){a[i][4], a[i][5], a[i][6], a[i][7]};
    }
  }
}

// ---------------------------------------------------------------------------
// Kernel 4: Mt[b][r][w] = bf16( 2g * sum_s Cinv[r][s] * N[s][w] )
// grid (32 w-chunks, 8 batch), 256 thr. K=128 (2 iters of BK=64).
// A = 2g*Cinv (fp32->bf16 staged), Bt = NT rows (w, contiguous s).
// ---------------------------------------------------------------------------
__global__ __launch_bounds__(256) void k_mt(const float* __restrict__ Cinv,
                                            const unsigned short* __restrict__ NT,
                                            const float* __restrict__ gamma,
                                            unsigned short* __restrict__ Mt) {
  __attribute__((aligned(16))) __shared__ unsigned short la[128 * 72];
  __attribute__((aligned(16))) __shared__ unsigned short lb[128 * 72];
  int wc = blockIdx.x, b = blockIdx.y;
  int w0 = wc * 128;
  float ga2 = 2.f * gamma[b];
  const float* Cb = Cinv + ((size_t)b << 14);
  const unsigned short* NTb = NT + (size_t)b * 524288;
  int t = threadIdx.x, wave = t >> 6, lane = t & 63, quad = lane >> 4, l16 = lane & 15;
  f32x4 acc[2][8];
#pragma unroll
  for (int i = 0; i < 2; i++)
#pragma unroll
    for (int j = 0; j < 8; j++) acc[i][j] = (f32x4){0.f, 0.f, 0.f, 0.f};
  int row = t >> 1, half = t & 1;
  const float* asrc = Cb + (size_t)row * 128 + half * 32;
  const unsigned short* bsrc = NTb + (size_t)(w0 + row) * 128 + half * 32;
  unsigned short* adst = la + row * 72 + half * 32;
  unsigned short* bdst = lb + row * 72 + half * 32;
  for (int it = 0; it < 2; ++it) {
    int k0 = it * 64;
    u32x4 pa0, pa1;
    {
      f32x4 v0 = *(const f32x4*)(asrc + k0 + 0);
      f32x4 v1 = *(const f32x4*)(asrc + k0 + 4);
      f32x4 v2 = *(const f32x4*)(asrc + k0 + 8);
      f32x4 v3 = *(const f32x4*)(asrc + k0 + 12);
      pa0[0] = pack2(ga2 * v0[0], ga2 * v0[1]); pa0[1] = pack2(ga2 * v0[2], ga2 * v0[3]);
      pa0[2] = pack2(ga2 * v1[0], ga2 * v1[1]); pa0[3] = pack2(ga2 * v1[2], ga2 * v1[3]);
      pa1[0] = pack2(ga2 * v2[0], ga2 * v2[1]); pa1[1] = pack2(ga2 * v2[2], ga2 * v2[3]);
      pa1[2] = pack2(ga2 * v3[0], ga2 * v3[1]); pa1[3] = pack2(ga2 * v3[2], ga2 * v3[3]);
    }
    u32x4 pa2, pa3;
    {
      f32x4 v0 = *(const f32x4*)(asrc + k0 + 16);
      f32x4 v1 = *(const f32x4*)(asrc + k0 + 20);
      f32x4 v2 = *(const f32x4*)(asrc + k0 + 24);
      f32x4 v3 = *(const f32x4*)(asrc + k0 + 28);
      pa2[0] = pack2(ga2 * v0[0], ga2 * v0[1]); pa2[1] = pack2(ga2 * v0[2], ga2 * v0[3]);
      pa2[2] = pack2(ga2 * v1[0], ga2 * v1[1]); pa2[3] = pack2(ga2 * v1[2], ga2 * v1[3]);
      pa3[0] = pack2(ga2 * v2[0], ga2 * v2[1]); pa3[1] = pack2(ga2 * v2[2], ga2 * v2[3]);
      pa3[2] = pack2(ga2 * v3[0], ga2 * v3[1]); pa3[3] = pack2(ga2 * v3[2], ga2 * v3[3]);
    }
    u32x4 bv0 = *(const u32x4*)(bsrc + k0 + 0);
    u32x4 bv1 = *(const u32x4*)(bsrc + k0 + 8);
    u32x4 bv2 = *(const u32x4*)(bsrc + k0 + 16);
    u32x4 bv3 = *(const u32x4*)(bsrc + k0 + 24);
    __syncthreads();
    *(u32x4*)(adst + 0) = pa0;  *(u32x4*)(adst + 8) = pa1;
    *(u32x4*)(adst + 16) = pa2; *(u32x4*)(adst + 24) = pa3;
    *(u32x4*)(bdst + 0) = bv0;  *(u32x4*)(bdst + 8) = bv1;
    *(u32x4*)(bdst + 16) = bv2; *(u32x4*)(bdst + 24) = bv3;
    __syncthreads();
    bf16x8 af[2][2], bfv[8][2];
#pragma unroll
    for (int mt = 0; mt < 2; mt++)
#pragma unroll
      for (int kk = 0; kk < 2; kk++)
        af[mt][kk] = *(const bf16x8*)(la + (wave * 32 + mt * 16 + l16) * 72 + (kk * 4 + quad) * 8);
#pragma unroll
    for (int nt = 0; nt < 8; nt++)
#pragma unroll
      for (int kk = 0; kk < 2; kk++)
        bfv[nt][kk] = *(const bf16x8*)(lb + (nt * 16 + l16) * 72 + (kk * 4 + quad) * 8);
#pragma unroll
    for (int mt = 0; mt < 2; mt++)
#pragma unroll
      for (int nt = 0; nt < 8; nt++)
#pragma unroll
        for (int kk = 0; kk < 2; kk++)
          acc[mt][nt] = MFMA16(af[mt][kk], bfv[nt][kk], acc[mt][nt]);
    __syncthreads();
  }
  unsigned short* Mb = Mt + (size_t)b * 524288;
#pragma unroll
  for (int mt = 0; mt < 2; mt++)
#pragma unroll
    for (int nt = 0; nt < 8; nt++)
#pragma unroll
      for (int rg = 0; rg < 4; rg++) {
        int r = wave * 32 + mt * 16 + quad * 4 + rg;
        int w = w0 + nt * 16 + l16;
        Mb[(size_t)r * 4096 + w] = f2bf(acc[mt][nt][rg]);
      }
}

// ---------------------------------------------------------------------------
// Kernel 5: big GEMM  out[b][h][r] = sum_w A[b][h][w] * Mt[b][r][w]
// grid (64 m-tiles, 8 batch) = 512 blocks (2/CU), 256 thr (4 waves).
// Tile 64(h) x 128(r), BK=64; A fp32->bf16 converted in-register.
// Memory-bound: 512 MB A stream -> ~86 us floor.
// ---------------------------------------------------------------------------
__global__ __launch_bounds__(256) void k_gemm(const float* __restrict__ A,
                                              const unsigned short* __restrict__ Mt,
                                              float* __restrict__ out) {
  __attribute__((aligned(16))) __shared__ unsigned short la[64 * 72];
  __attribute__((aligned(16))) __shared__ unsigned short lb[128 * 72];
  int mtile = blockIdx.x, b = blockIdx.y;
  const float* Ab = A + (size_t)b * 16777216 + (size_t)mtile * 64 * 4096;
  const unsigned short* Mb = Mt + (size_t)b * 524288;
  int t = threadIdx.x, wave = t >> 6, lane = t & 63, quad = lane >> 4, l16 = lane & 15;
  int wm = wave >> 1, wr = wave & 1;  // 2x2 wave grid: 32(h) x 64(r) per wave
  f32x4 acc[2][4];
#pragma unroll
  for (int i = 0; i < 2; i++)
#pragma unroll
    for (int j = 0; j < 4; j++) acc[i][j] = (f32x4){0.f, 0.f, 0.f, 0.f};
  int arow = t >> 2, aq = t & 3;   // A stage: 64 rows x 4 col-quarters of 16
  int brow = t >> 1, bhalf = t & 1;  // B stage: 128 rows x 2 halves of 32
  const float* asrc = Ab + (size_t)arow * 4096 + aq * 16;
  const unsigned short* bsrc = Mb + (size_t)brow * 4096 + bhalf * 32;
  unsigned short* adst = la + arow * 72 + aq * 16;
  unsigned short* bdst = lb + brow * 72 + bhalf * 32;
  for (int it = 0; it < 64; ++it) {
    int k0 = it * 64;
    f32x4 av0 = *(const f32x4*)(asrc + k0 + 0);
    f32x4 av1 = *(const f32x4*)(asrc + k0 + 4);
    f32x4 av2 = *(const f32x4*)(asrc + k0 + 8);
    f32x4 av3 = *(const f32x4*)(asrc + k0 + 12);
    u32x4 bv0 = *(const u32x4*)(bsrc + k0 + 0);
    u32x4 bv1 = *(const u32x4*)(bsrc + k0 + 8);
    u32x4 bv2 = *(const u32x4*)(bsrc + k0 + 16);
    u32x4 bv3 = *(const u32x4*)(bsrc + k0 + 24);
    u32x4 pa0, pa1;
    pa0[0] = pack2(av0[0], av0[1]); pa0[1] = pack2(av0[2], av0[3]);
    pa0[2] = pack2(av1[0], av1[1]); pa0[3] = pack2(av1[2], av1[3]);
    pa1[0] = pack2(av2[0], av2[1]); pa1[1] = pack2(av2[2], av2[3]);
    pa1[2] = pack2(av3[0], av3[1]); pa1[3] = pack2(av3[2], av3[3]);
    __syncthreads();
    *(u32x4*)(adst + 0) = pa0;
    *(u32x4*)(adst + 8) = pa1;
    *(u32x4*)(bdst + 0) = bv0;
    *(u32x4*)(bdst + 8) = bv1;
    *(u32x4*)(bdst + 16) = bv2;
    *(u32x4*)(bdst + 24) = bv3;
    __syncthreads();
    bf16x8 af[2][2], bfv[4][2];
#pragma unroll
    for (int mt = 0; mt < 2; mt++)
#pragma unroll
      for (int kk = 0; kk < 2; kk++)
        af[mt][kk] = *(const bf16x8*)(la + (wm * 32 + mt * 16 + l16) * 72 + (kk * 4 + quad) * 8);
#pragma unroll
    for (int rt = 0; rt < 4; rt++)
#pragma unroll
      for (int kk = 0; kk < 2; kk++)
        bfv[rt][kk] = *(const bf16x8*)(lb + (wr * 64 + rt * 16 + l16) * 72 + (kk * 4 + quad) * 8);
#pragma unroll
    for (int mt = 0; mt < 2; mt++)
#pragma unroll
      for (int rt = 0; rt < 4; rt++)
#pragma unroll
        for (int kk = 0; kk < 2; kk++)
          acc[mt][rt] = MFMA16(af[mt][kk], bfv[rt][kk], acc[mt][rt]);
  }
  float* ob = out + (size_t)b * 524288 + (size_t)mtile * 64 * 128;
#pragma unroll
  for (int mt = 0; mt < 2; mt++)
#pragma unroll
    for (int rt = 0; rt < 4; rt++)
#pragma unroll
      for (int rg = 0; rg < 4; rg++) {
        int h = wm * 32 + mt * 16 + quad * 4 + rg;
        int r = wr * 64 + rt * 16 + l16;
        ob[h * 128 + r] = acc[mt][rt][rg];
      }
}

// ---------------------------------------------------------------------------
extern "C" void kernel_launch(void* const* d_in, const int* in_sizes, int n_in,
                              void* d_out, int out_size, void* d_ws, size_t ws_size,
                              hipStream_t stream) {
  const float* N = (const float*)d_in[0];
  const float* Ak = (const float*)d_in[1];
  const float* alpha = (const float*)d_in[2];
  const float* gamma = (const float*)d_in[3];
  float* out = (float*)d_out;
  char* ws = (char*)d_ws;
  // workspace layout (total ~18.5 MB)
  unsigned short* NT = (unsigned short*)(ws);              // 8 MB : N^T bf16
  float* Gpart = (float*)(ws + 8388608);                   // 2 MB : gram partials
  float* Cinv = (float*)(ws + 10485760);                   // 512KB: fp32 inverses
  unsigned short* Mt = (unsigned short*)(ws + 11010048);   // 8 MB : 2g*Cinv*N bf16

  k_castT<<<dim3(64, 8), 256, 0, stream>>>(N, NT);
  k_gram<<<dim3(4, 8), 256, 0, stream>>>(N, Gpart);
  k_inv<<<dim3(8), 1024, 0, stream>>>(Gpart, alpha, gamma, Cinv);
  k_mt<<<dim3(32, 8), 256, 0, stream>>>(Cinv, NT, gamma, Mt);
  k_gemm<<<dim3(64, 8), 256, 0, stream>>>(Ak, Mt, out);
}

// Round 2
// 858.941 us; speedup vs baseline: 1.0350x; 1.0350x over previous
//
#include <hip/hip_runtime.h>

// ---------------------------------------------------------------------------
// Problem: B=8, R=128, H=W=4096
//   C    = alpha*I + 2*gamma * N @ N^T            [128x128], SPD, diag-dominant
//   out  = Ak_L @ (2*gamma * Cinv @ N)^T          [4096x128] per batch
// Pipeline:
//   k_castT : N fp32 [r][w] -> NT bf16 [w][r]
//   k_gram  : Gpart[b][ks] = partial N*N^T (bf16 MFMA, K split by 8)
//   k_inv   : C = alpha*I + 2g*sum(Gpart); in-place fp32 Gauss-Jordan inverse
//             (1 barrier/step, parity double-buffered pivot row/col)
//   k_mt    : Mt = bf16(2g * Cinv @ N)  via MFMA
//   k_gemm  : out = A(fp32->bf16) @ Mt^T  -- register-prefetch pipelined,
//             XCD-swizzled (b = blk&7). Memory-bound: ~92 us floor.
// ---------------------------------------------------------------------------

typedef __attribute__((ext_vector_type(8))) short bf16x8;
typedef __attribute__((ext_vector_type(4))) float f32x4;
typedef __attribute__((ext_vector_type(4))) unsigned int u32x4;

#define MFMA16(a, b, c) __builtin_amdgcn_mfma_f32_16x16x32_bf16((a), (b), (c), 0, 0, 0)
#define NSPLIT 8

__device__ __forceinline__ unsigned short f2bf(float f) {
  union { float f; unsigned u; } v; v.f = f;
  unsigned u = v.u;
  return (unsigned short)((u + 0x7FFFu + ((u >> 16) & 1u)) >> 16);  // RNE
}
__device__ __forceinline__ unsigned pack2(float x, float y) {
  return (unsigned)f2bf(x) | ((unsigned)f2bf(y) << 16);
}

// ---------------------------------------------------------------------------
// Kernel 1: transposed cast  N[b][r][w] fp32 -> NT[b][w][r] bf16
// grid (64, 8), 256 thr; tile 128r x 64w through LDS
// ---------------------------------------------------------------------------
__global__ __launch_bounds__(256) void k_castT(const float* __restrict__ N,
                                               unsigned short* __restrict__ NT) {
  __attribute__((aligned(16))) __shared__ float tile[128 * 68];
  int wc = blockIdx.x, b = blockIdx.y;
  const float* Nb = N + (size_t)b * 524288 + wc * 64;
  int t = threadIdx.x;
  int row = t >> 1, half = t & 1;
  const float* src = Nb + (size_t)row * 4096 + half * 32;
  float* dst = tile + row * 68 + half * 32;
#pragma unroll
  for (int j = 0; j < 8; j++) *(f32x4*)(dst + j * 4) = *(const f32x4*)(src + j * 4);
  __syncthreads();
  int ow = t >> 2, q = t & 3;
  unsigned short* out = NT + (size_t)b * 524288 + (size_t)(wc * 64 + ow) * 128 + q * 32;
#pragma unroll
  for (int c = 0; c < 4; c++) {
    u32x4 p;
#pragma unroll
    for (int k = 0; k < 4; k++) {
      float f0 = tile[(q * 32 + c * 8 + k * 2) * 68 + ow];
      float f1 = tile[(q * 32 + c * 8 + k * 2 + 1) * 68 + ow];
      p[k] = pack2(f0, f1);
    }
    *(u32x4*)(out + c * 8) = p;
  }
}

// ---------------------------------------------------------------------------
// Kernel 2: Gram partials. grid (NSPLIT=8, 8 batch) = 64 blocks, 256 thr.
// Gpart[b][ks][128][128] fp32 = N[:, ks*512 : +512] @ same^T  (bf16 MFMA)
// ---------------------------------------------------------------------------
__global__ __launch_bounds__(256) void k_gram(const float* __restrict__ N,
                                              float* __restrict__ Gpart) {
  __attribute__((aligned(16))) __shared__ unsigned short lds[128 * 72];
  int ks = blockIdx.x, b = blockIdx.y;
  const float* Nb = N + (size_t)b * 524288 + ks * 512;
  int t = threadIdx.x;
  int wave = t >> 6, lane = t & 63, quad = lane >> 4, l16 = lane & 15;
  f32x4 acc[2][8];
#pragma unroll
  for (int i = 0; i < 2; i++)
#pragma unroll
    for (int j = 0; j < 8; j++) acc[i][j] = (f32x4){0.f, 0.f, 0.f, 0.f};
  int srow = t >> 1, shalf = t & 1;
  const float* srcb = Nb + (size_t)srow * 4096 + shalf * 32;
  unsigned short* dptr = lds + srow * 72 + shalf * 32;
  for (int it = 0; it < 8; ++it) {
    u32x4 pk0, pk1;
    {
      f32x4 v0 = *(const f32x4*)(srcb + it * 64 + 0);
      f32x4 v1 = *(const f32x4*)(srcb + it * 64 + 4);
      f32x4 v2 = *(const f32x4*)(srcb + it * 64 + 8);
      f32x4 v3 = *(const f32x4*)(srcb + it * 64 + 12);
      pk0[0] = pack2(v0[0], v0[1]); pk0[1] = pack2(v0[2], v0[3]);
      pk0[2] = pack2(v1[0], v1[1]); pk0[3] = pack2(v1[2], v1[3]);
      pk1[0] = pack2(v2[0], v2[1]); pk1[1] = pack2(v2[2], v2[3]);
      pk1[2] = pack2(v3[0], v3[1]); pk1[3] = pack2(v3[2], v3[3]);
    }
    u32x4 pk2, pk3;
    {
      f32x4 v0 = *(const f32x4*)(srcb + it * 64 + 16);
      f32x4 v1 = *(const f32x4*)(srcb + it * 64 + 20);
      f32x4 v2 = *(const f32x4*)(srcb + it * 64 + 24);
      f32x4 v3 = *(const f32x4*)(srcb + it * 64 + 28);
      pk2[0] = pack2(v0[0], v0[1]); pk2[1] = pack2(v0[2], v0[3]);
      pk2[2] = pack2(v1[0], v1[1]); pk2[3] = pack2(v1[2], v1[3]);
      pk3[0] = pack2(v2[0], v2[1]); pk3[1] = pack2(v2[2], v2[3]);
      pk3[2] = pack2(v3[0], v3[1]); pk3[3] = pack2(v3[2], v3[3]);
    }
    __syncthreads();
    *(u32x4*)(dptr + 0) = pk0;
    *(u32x4*)(dptr + 8) = pk1;
    *(u32x4*)(dptr + 16) = pk2;
    *(u32x4*)(dptr + 24) = pk3;
    __syncthreads();
    bf16x8 af[2][2], bfv[8][2];
#pragma unroll
    for (int mt = 0; mt < 2; mt++)
#pragma unroll
      for (int kk = 0; kk < 2; kk++)
        af[mt][kk] = *(const bf16x8*)(lds + (wave * 32 + mt * 16 + l16) * 72 + (kk * 4 + quad) * 8);
#pragma unroll
    for (int nt = 0; nt < 8; nt++)
#pragma unroll
      for (int kk = 0; kk < 2; kk++)
        bfv[nt][kk] = *(const bf16x8*)(lds + (nt * 16 + l16) * 72 + (kk * 4 + quad) * 8);
#pragma unroll
    for (int mt = 0; mt < 2; mt++)
#pragma unroll
      for (int nt = 0; nt < 8; nt++)
#pragma unroll
        for (int kk = 0; kk < 2; kk++)
          acc[mt][nt] = MFMA16(af[mt][kk], bfv[nt][kk], acc[mt][nt]);
  }
  float* Gp = Gpart + ((size_t)(b * NSPLIT + ks) << 14);
#pragma unroll
  for (int mt = 0; mt < 2; mt++)
#pragma unroll
    for (int nt = 0; nt < 8; nt++)
#pragma unroll
      for (int rg = 0; rg < 4; rg++) {
        int row = wave * 32 + mt * 16 + quad * 4 + rg;
        int col = nt * 16 + l16;
        Gp[row * 128 + col] = acc[mt][nt][rg];
      }
}

// ---------------------------------------------------------------------------
// Kernel 3: in-place Gauss-Jordan inverse of C = alpha*I + 2g*sum(Gpart).
// grid (8), 1024 thr. Thread (rb=t>>5, cg=t&31) owns 4 rows x 4 cols.
// Standard in-place GJ (no pivoting; C SPD + diag-dominant):
//   d=a[p][p]; a[p][p]=1/d; a[p][j]=a[p][j]/d; a[i][p]=-a[i][p]/d;
//   a[i][j]-=a[i][p]*a[p][j]/d
// ONE barrier/step: capture col p + row p (pre-update, own regs) into
// parity-double-buffered LDS, barrier, rank-1 update.
// ---------------------------------------------------------------------------
__global__ __launch_bounds__(1024) void k_inv(const float* __restrict__ Gpart,
                                              const float* __restrict__ alpha,
                                              const float* __restrict__ gamma,
                                              float* __restrict__ Cinv) {
  __attribute__((aligned(16))) __shared__ float Cs[16384];
  __attribute__((aligned(16))) __shared__ float mcol[2][128];
  __attribute__((aligned(16))) __shared__ float pivrow[2][128];
  int b = blockIdx.x;
  int t = threadIdx.x;
  const float* Gp = Gpart + ((size_t)b * NSPLIT << 14);
#pragma unroll
  for (int c = 0; c < 4; c++) {
    int off = c * 4096 + t * 4;
    f32x4 s = (f32x4){0.f, 0.f, 0.f, 0.f};
#pragma unroll
    for (int ks = 0; ks < NSPLIT; ks++) s += *(const f32x4*)(Gp + ks * 16384 + off);
    *(f32x4*)(Cs + off) = s;
  }
  __syncthreads();
  int cg = t & 31, rb = t >> 5;  // cg fastest -> coalesced epilogue
  float al = alpha[b], ga2 = 2.f * gamma[b];
  float a[4][4];
#pragma unroll
  for (int i = 0; i < 4; i++) {
    int r = rb * 4 + i;
    f32x4 v = *(const f32x4*)(Cs + r * 128 + cg * 4);
#pragma unroll
    for (int j = 0; j < 4; j++) {
      int c = cg * 4 + j;
      a[i][j] = ga2 * v[j] + ((r == c) ? al : 0.f);
    }
  }
  for (int p = 0; p < 128; ++p) {
    int pb = p & 1;
    int cgp = p >> 2, jp = p & 3;
    int rbp = p >> 2, ip = p & 3;
    if (cg == cgp) {  // capture column p (own regs, pre-update)
      f32x4 mv;
#pragma unroll
      for (int i = 0; i < 4; i++)
        mv[i] = (jp & 2) ? ((jp & 1) ? a[i][3] : a[i][2]) : ((jp & 1) ? a[i][1] : a[i][0]);
      *(f32x4*)&mcol[pb][rb * 4] = mv;
    }
    if (rb == rbp) {  // capture row p (unnormalized)
      f32x4 pv;
#pragma unroll
      for (int j = 0; j < 4; j++)
        pv[j] = (ip & 2) ? ((ip & 1) ? a[3][j] : a[2][j]) : ((ip & 1) ? a[1][j] : a[0][j]);
      *(f32x4*)&pivrow[pb][cg * 4] = pv;
    }
    __syncthreads();
    float invd = 1.0f / mcol[pb][p];  // mcol[p] == a[p][p]
    f32x4 mc = *(const f32x4*)&mcol[pb][rb * 4];
    f32x4 pr = *(const f32x4*)&pivrow[pb][cg * 4];
#pragma unroll
    for (int i = 0; i < 4; i++) {
      int r = rb * 4 + i;
      float mi = mc[i] * invd;
#pragma unroll
      for (int j = 0; j < 4; j++) {
        int c = cg * 4 + j;
        float v = a[i][j] - mi * pr[j];
        if (c == p) v = -mi;
        if (r == p) v = pr[j] * invd;
        if (r == p && c == p) v = invd;
        a[i][j] = v;
      }
    }
    // no second barrier: next capture writes the OTHER parity buffer and
    // reads only the capturing thread's own (in-order updated) registers.
  }
  float* dst = Cinv + ((size_t)b << 14);
#pragma unroll
  for (int i = 0; i < 4; i++) {
    int r = rb * 4 + i;
    *(f32x4*)(dst + r * 128 + cg * 4) = (f32x4){a[i][0], a[i][1], a[i][2], a[i][3]};
  }
}

// ---------------------------------------------------------------------------
// Kernel 4: Mt[b][r][w] = bf16( 2g * sum_s Cinv[r][s] * N[s][w] )
// grid (32 w-chunks, 8 batch), 256 thr. K=128 (2 iters of BK=64).
// ---------------------------------------------------------------------------
__global__ __launch_bounds__(256) void k_mt(const float* __restrict__ Cinv,
                                            const unsigned short* __restrict__ NT,
                                            const float* __restrict__ gamma,
                                            unsigned short* __restrict__ Mt) {
  __attribute__((aligned(16))) __shared__ unsigned short la[128 * 72];
  __attribute__((aligned(16))) __shared__ unsigned short lb[128 * 72];
  int wc = blockIdx.x, b = blockIdx.y;
  int w0 = wc * 128;
  float ga2 = 2.f * gamma[b];
  const float* Cb = Cinv + ((size_t)b << 14);
  const unsigned short* NTb = NT + (size_t)b * 524288;
  int t = threadIdx.x, wave = t >> 6, lane = t & 63, quad = lane >> 4, l16 = lane & 15;
  f32x4 acc[2][8];
#pragma unroll
  for (int i = 0; i < 2; i++)
#pragma unroll
    for (int j = 0; j < 8; j++) acc[i][j] = (f32x4){0.f, 0.f, 0.f, 0.f};
  int row = t >> 1, half = t & 1;
  const float* asrc = Cb + (size_t)row * 128 + half * 32;
  const unsigned short* bsrc = NTb + (size_t)(w0 + row) * 128 + half * 32;
  unsigned short* adst = la + row * 72 + half * 32;
  unsigned short* bdst = lb + row * 72 + half * 32;
  for (int it = 0; it < 2; ++it) {
    int k0 = it * 64;
    u32x4 pa0, pa1;
    {
      f32x4 v0 = *(const f32x4*)(asrc + k0 + 0);
      f32x4 v1 = *(const f32x4*)(asrc + k0 + 4);
      f32x4 v2 = *(const f32x4*)(asrc + k0 + 8);
      f32x4 v3 = *(const f32x4*)(asrc + k0 + 12);
      pa0[0] = pack2(ga2 * v0[0], ga2 * v0[1]); pa0[1] = pack2(ga2 * v0[2], ga2 * v0[3]);
      pa0[2] = pack2(ga2 * v1[0], ga2 * v1[1]); pa0[3] = pack2(ga2 * v1[2], ga2 * v1[3]);
      pa1[0] = pack2(ga2 * v2[0], ga2 * v2[1]); pa1[1] = pack2(ga2 * v2[2], ga2 * v2[3]);
      pa1[2] = pack2(ga2 * v3[0], ga2 * v3[1]); pa1[3] = pack2(ga2 * v3[2], ga2 * v3[3]);
    }
    u32x4 pa2, pa3;
    {
      f32x4 v0 = *(const f32x4*)(asrc + k0 + 16);
      f32x4 v1 = *(const f32x4*)(asrc + k0 + 20);
      f32x4 v2 = *(const f32x4*)(asrc + k0 + 24);
      f32x4 v3 = *(const f32x4*)(asrc + k0 + 28);
      pa2[0] = pack2(ga2 * v0[0], ga2 * v0[1]); pa2[1] = pack2(ga2 * v0[2], ga2 * v0[3]);
      pa2[2] = pack2(ga2 * v1[0], ga2 * v1[1]); pa2[3] = pack2(ga2 * v1[2], ga2 * v1[3]);
      pa3[0] = pack2(ga2 * v2[0], ga2 * v2[1]); pa3[1] = pack2(ga2 * v2[2], ga2 * v2[3]);
      pa3[2] = pack2(ga2 * v3[0], ga2 * v3[1]); pa3[3] = pack2(ga2 * v3[2], ga2 * v3[3]);
    }
    u32x4 bv0 = *(const u32x4*)(bsrc + k0 + 0);
    u32x4 bv1 = *(const u32x4*)(bsrc + k0 + 8);
    u32x4 bv2 = *(const u32x4*)(bsrc + k0 + 16);
    u32x4 bv3 = *(const u32x4*)(bsrc + k0 + 24);
    __syncthreads();
    *(u32x4*)(adst + 0) = pa0;  *(u32x4*)(adst + 8) = pa1;
    *(u32x4*)(adst + 16) = pa2; *(u32x4*)(adst + 24) = pa3;
    *(u32x4*)(bdst + 0) = bv0;  *(u32x4*)(bdst + 8) = bv1;
    *(u32x4*)(bdst + 16) = bv2; *(u32x4*)(bdst + 24) = bv3;
    __syncthreads();
    bf16x8 af[2][2], bfv[8][2];
#pragma unroll
    for (int mt = 0; mt < 2; mt++)
#pragma unroll
      for (int kk = 0; kk < 2; kk++)
        af[mt][kk] = *(const bf16x8*)(la + (wave * 32 + mt * 16 + l16) * 72 + (kk * 4 + quad) * 8);
#pragma unroll
    for (int nt = 0; nt < 8; nt++)
#pragma unroll
      for (int kk = 0; kk < 2; kk++)
        bfv[nt][kk] = *(const bf16x8*)(lb + (nt * 16 + l16) * 72 + (kk * 4 + quad) * 8);
#pragma unroll
    for (int mt = 0; mt < 2; mt++)
#pragma unroll
      for (int nt = 0; nt < 8; nt++)
#pragma unroll
        for (int kk = 0; kk < 2; kk++)
          acc[mt][nt] = MFMA16(af[mt][kk], bfv[nt][kk], acc[mt][nt]);
    __syncthreads();
  }
  unsigned short* Mb = Mt + (size_t)b * 524288;
#pragma unroll
  for (int mt = 0; mt < 2; mt++)
#pragma unroll
    for (int nt = 0; nt < 8; nt++)
#pragma unroll
      for (int rg = 0; rg < 4; rg++) {
        int r = wave * 32 + mt * 16 + quad * 4 + rg;
        int w = w0 + nt * 16 + l16;
        Mb[(size_t)r * 4096 + w] = f2bf(acc[mt][nt][rg]);
      }
}

// ---------------------------------------------------------------------------
// Kernel 5: big GEMM  out[b][h][r] = sum_w A[b][h][w] * Mt[b][r][w]
// grid 512 1D: b = blk&7 (XCD-swizzle: each XCD's L2 caches one batch's Mt),
// mtile = blk>>3. 256 thr (4 waves), tile 64(h) x 128(r), BK=64.
// Register-prefetch pipeline: loads for iter k+1 issue before MFMA of iter k;
// the vmcnt wait lands at next iter's pack, ~1 full iter after issue.
// ---------------------------------------------------------------------------
__global__ __launch_bounds__(256) void k_gemm(const float* __restrict__ A,
                                              const unsigned short* __restrict__ Mt,
                                              float* __restrict__ out) {
  __attribute__((aligned(16))) __shared__ unsigned short la[64 * 72];
  __attribute__((aligned(16))) __shared__ unsigned short lb[128 * 72];
  int blk = blockIdx.x;
  int b = blk & 7, mtile = blk >> 3;
  const float* Ab = A + (size_t)b * 16777216 + (size_t)mtile * 64 * 4096;
  const unsigned short* Mb = Mt + (size_t)b * 524288;
  int t = threadIdx.x, wave = t >> 6, lane = t & 63, quad = lane >> 4, l16 = lane & 15;
  int wm = wave >> 1, wr = wave & 1;
  f32x4 acc[2][4];
#pragma unroll
  for (int i = 0; i < 2; i++)
#pragma unroll
    for (int j = 0; j < 4; j++) acc[i][j] = (f32x4){0.f, 0.f, 0.f, 0.f};
  int arow = t >> 2, aq = t & 3;
  int brow = t >> 1, bhalf = t & 1;
  const float* asrc = Ab + (size_t)arow * 4096 + aq * 16;
  const unsigned short* bsrc = Mb + (size_t)brow * 4096 + bhalf * 32;
  unsigned short* adst = la + arow * 72 + aq * 16;
  unsigned short* bdst = lb + brow * 72 + bhalf * 32;
  // prologue: prefetch iter 0
  f32x4 av0 = *(const f32x4*)(asrc + 0);
  f32x4 av1 = *(const f32x4*)(asrc + 4);
  f32x4 av2 = *(const f32x4*)(asrc + 8);
  f32x4 av3 = *(const f32x4*)(asrc + 12);
  u32x4 bv0 = *(const u32x4*)(bsrc + 0);
  u32x4 bv1 = *(const u32x4*)(bsrc + 8);
  u32x4 bv2 = *(const u32x4*)(bsrc + 16);
  u32x4 bv3 = *(const u32x4*)(bsrc + 24);
  for (int it = 0; it < 64; ++it) {
    u32x4 pa0, pa1;  // pack (this is where the vmcnt wait lands)
    pa0[0] = pack2(av0[0], av0[1]); pa0[1] = pack2(av0[2], av0[3]);
    pa0[2] = pack2(av1[0], av1[1]); pa0[3] = pack2(av1[2], av1[3]);
    pa1[0] = pack2(av2[0], av2[1]); pa1[1] = pack2(av2[2], av2[3]);
    pa1[2] = pack2(av3[0], av3[1]); pa1[3] = pack2(av3[2], av3[3]);
    __syncthreads();
    *(u32x4*)(adst + 0) = pa0;
    *(u32x4*)(adst + 8) = pa1;
    *(u32x4*)(bdst + 0) = bv0;
    *(u32x4*)(bdst + 8) = bv1;
    *(u32x4*)(bdst + 16) = bv2;
    *(u32x4*)(bdst + 24) = bv3;
    __syncthreads();
    if (it < 63) {  // prefetch next iter before MFMA section
      int k0 = (it + 1) * 64;
      av0 = *(const f32x4*)(asrc + k0 + 0);
      av1 = *(const f32x4*)(asrc + k0 + 4);
      av2 = *(const f32x4*)(asrc + k0 + 8);
      av3 = *(const f32x4*)(asrc + k0 + 12);
      bv0 = *(const u32x4*)(bsrc + k0 + 0);
      bv1 = *(const u32x4*)(bsrc + k0 + 8);
      bv2 = *(const u32x4*)(bsrc + k0 + 16);
      bv3 = *(const u32x4*)(bsrc + k0 + 24);
    }
    bf16x8 af[2][2], bfv[4][2];
#pragma unroll
    for (int mt = 0; mt < 2; mt++)
#pragma unroll
      for (int kk = 0; kk < 2; kk++)
        af[mt][kk] = *(const bf16x8*)(la + (wm * 32 + mt * 16 + l16) * 72 + (kk * 4 + quad) * 8);
#pragma unroll
    for (int rt = 0; rt < 4; rt++)
#pragma unroll
      for (int kk = 0; kk < 2; kk++)
        bfv[rt][kk] = *(const bf16x8*)(lb + (wr * 64 + rt * 16 + l16) * 72 + (kk * 4 + quad) * 8);
#pragma unroll
    for (int mt = 0; mt < 2; mt++)
#pragma unroll
      for (int rt = 0; rt < 4; rt++)
#pragma unroll
        for (int kk = 0; kk < 2; kk++)
          acc[mt][rt] = MFMA16(af[mt][kk], bfv[rt][kk], acc[mt][rt]);
  }
  float* ob = out + (size_t)b * 524288 + (size_t)mtile * 64 * 128;
#pragma unroll
  for (int mt = 0; mt < 2; mt++)
#pragma unroll
    for (int rt = 0; rt < 4; rt++)
#pragma unroll
      for (int rg = 0; rg < 4; rg++) {
        int h = wm * 32 + mt * 16 + quad * 4 + rg;
        int r = wr * 64 + rt * 16 + l16;
        ob[h * 128 + r] = acc[mt][rt][rg];
      }
}

// ---------------------------------------------------------------------------
extern "C" void kernel_launch(void* const* d_in, const int* in_sizes, int n_in,
                              void* d_out, int out_size, void* d_ws, size_t ws_size,
                              hipStream_t stream) {
  const float* N = (const float*)d_in[0];
  const float* Ak = (const float*)d_in[1];
  const float* alpha = (const float*)d_in[2];
  const float* gamma = (const float*)d_in[3];
  float* out = (float*)d_out;
  char* ws = (char*)d_ws;
  // workspace layout (~20.5 MB)
  unsigned short* NT = (unsigned short*)(ws);              // 8 MB : N^T bf16
  float* Gpart = (float*)(ws + 8388608);                   // 4 MB : gram partials
  float* Cinv = (float*)(ws + 12582912);                   // 512KB: fp32 inverses
  unsigned short* Mt = (unsigned short*)(ws + 13107200);   // 8 MB : 2g*Cinv*N bf16

  k_castT<<<dim3(64, 8), 256, 0, stream>>>(N, NT);
  k_gram<<<dim3(NSPLIT, 8), 256, 0, stream>>>(N, Gpart);
  k_inv<<<dim3(8), 1024, 0, stream>>>(Gpart, alpha, gamma, Cinv);
  k_mt<<<dim3(32, 8), 256, 0, stream>>>(Cinv, NT, gamma, Mt);
  k_gemm<<<dim3(512), 256, 0, stream>>>(Ak, Mt, out);
}